// Round 1
// baseline (390.428 us; speedup 1.0000x reference)
//
#include <hip/hip_runtime.h>
#include <math.h>

#define WDIM 4096
#define SDIM 4096
#define NKEYS 1024
#define SHARP 10.0f

__device__ __forceinline__ float wave_reduce_sum(float v) {
#pragma unroll
    for (int off = 32; off > 0; off >>= 1) v += __shfl_down(v, off, 64);
    return v;
}

// K1: noisy_mix[w] = sum_s holo[w,s] * conj(cue[w,s])
// re = hr*cr + hi*ci ; im = hi*cr - hr*ci
__global__ __launch_bounds__(256) void k_mix(
    const float* __restrict__ hr, const float* __restrict__ hi,
    const float* __restrict__ cr, const float* __restrict__ ci,
    float* __restrict__ mix_re, float* __restrict__ mix_im) {
    const int w = blockIdx.x;
    const size_t base = (size_t)w * SDIM;
    const float4* hr4 = (const float4*)(hr + base);
    const float4* hi4 = (const float4*)(hi + base);
    const float4* cr4 = (const float4*)(cr + base);
    const float4* ci4 = (const float4*)(ci + base);
    float sr = 0.f, si = 0.f;
#pragma unroll
    for (int i = threadIdx.x; i < SDIM / 4; i += 256) {
        float4 a = hr4[i], b = hi4[i], c = cr4[i], d = ci4[i];
        sr += a.x * c.x + b.x * d.x;  si += b.x * c.x - a.x * d.x;
        sr += a.y * c.y + b.y * d.y;  si += b.y * c.y - a.y * d.y;
        sr += a.z * c.z + b.z * d.z;  si += b.z * c.z - a.z * d.z;
        sr += a.w * c.w + b.w * d.w;  si += b.w * c.w - a.w * d.w;
    }
    sr = wave_reduce_sum(sr);
    si = wave_reduce_sum(si);
    __shared__ float lre[4], lim[4];
    const int wave = threadIdx.x >> 6, lane = threadIdx.x & 63;
    if (lane == 0) { lre[wave] = sr; lim[wave] = si; }
    __syncthreads();
    if (threadIdx.x == 0) {
        mix_re[w] = lre[0] + lre[1] + lre[2] + lre[3];
        mix_im[w] = lim[0] + lim[1] + lim[2] + lim[3];
    }
}

// K2: corr[n] = |sum_w keys[n,w] * mix[w]| * SHARP   (plain dot, NO conjugation)
// zr = kr*mr - ki*mi ; zi = kr*mi + ki*mr
__global__ __launch_bounds__(256) void k_corr(
    const float* __restrict__ kr, const float* __restrict__ ki,
    const float* __restrict__ mr, const float* __restrict__ mi,
    float* __restrict__ corr) {
    const int n = blockIdx.x;
    const size_t base = (size_t)n * WDIM;
    const float4* kr4 = (const float4*)(kr + base);
    const float4* ki4 = (const float4*)(ki + base);
    const float4* mr4 = (const float4*)mr;
    const float4* mi4 = (const float4*)mi;
    float zr = 0.f, zi = 0.f;
#pragma unroll
    for (int i = threadIdx.x; i < WDIM / 4; i += 256) {
        float4 a = kr4[i], b = ki4[i], m = mr4[i], q = mi4[i];
        zr += a.x * m.x - b.x * q.x;  zi += a.x * q.x + b.x * m.x;
        zr += a.y * m.y - b.y * q.y;  zi += a.y * q.y + b.y * m.y;
        zr += a.z * m.z - b.z * q.z;  zi += a.z * q.z + b.z * m.z;
        zr += a.w * m.w - b.w * q.w;  zi += a.w * q.w + b.w * m.w;
    }
    zr = wave_reduce_sum(zr);
    zi = wave_reduce_sum(zi);
    __shared__ float lre[4], lim[4];
    const int wave = threadIdx.x >> 6, lane = threadIdx.x & 63;
    if (lane == 0) { lre[wave] = zr; lim[wave] = zi; }
    __syncthreads();
    if (threadIdx.x == 0) {
        const float fr = lre[0] + lre[1] + lre[2] + lre[3];
        const float fi = lim[0] + lim[1] + lim[2] + lim[3];
        corr[n] = sqrtf(fr * fr + fi * fi) * SHARP;
    }
}

// K3: att = softmax(corr)  — single block, 256 threads, 4 logits/thread
__global__ __launch_bounds__(256) void k_softmax(
    const float* __restrict__ corr, float* __restrict__ att) {
    const int t = threadIdx.x;
    __shared__ float red[256];
    float v[4];
    float m = -1e30f;
#pragma unroll
    for (int j = 0; j < 4; ++j) { v[j] = corr[t + j * 256]; m = fmaxf(m, v[j]); }
    red[t] = m; __syncthreads();
    for (int s = 128; s > 0; s >>= 1) {
        if (t < s) red[t] = fmaxf(red[t], red[t + s]);
        __syncthreads();
    }
    const float mx = red[0];
    __syncthreads();
    float e[4]; float sum = 0.f;
#pragma unroll
    for (int j = 0; j < 4; ++j) { e[j] = expf(v[j] - mx); sum += e[j]; }
    red[t] = sum; __syncthreads();
    for (int s = 128; s > 0; s >>= 1) {
        if (t < s) red[t] += red[t + s];
        __syncthreads();
    }
    const float inv = 1.0f / red[0];
#pragma unroll
    for (int j = 0; j < 4; ++j) att[t + j * 256] = e[j] * inv;
}

// K4: clean_key[w] = sum_n att[n] * keys[n,w]   (column-wise weighted sum)
// block = 256 threads: 64 w-lanes x 4 n-groups; grid = WDIM/64 blocks
__global__ __launch_bounds__(256) void k_clean(
    const float* __restrict__ kr, const float* __restrict__ ki,
    const float* __restrict__ att,
    float* __restrict__ clean_re, float* __restrict__ clean_im) {
    __shared__ float s_att[NKEYS];
    for (int i = threadIdx.x; i < NKEYS; i += 256) s_att[i] = att[i];
    __syncthreads();
    const int lane = threadIdx.x & 63;
    const int grp = threadIdx.x >> 6;
    const int w = blockIdx.x * 64 + lane;
    float accr = 0.f, acci = 0.f;
    const int n0 = grp * 256;
#pragma unroll 8
    for (int n = n0; n < n0 + 256; ++n) {
        const float a = s_att[n];
        accr += a * kr[(size_t)n * WDIM + w];
        acci += a * ki[(size_t)n * WDIM + w];
    }
    __shared__ float sre[4][64], simg[4][64];
    sre[grp][lane] = accr; simg[grp][lane] = acci;
    __syncthreads();
    if (grp == 0) {
        clean_re[w] = sre[0][lane] + sre[1][lane] + sre[2][lane] + sre[3][lane];
        clean_im[w] = simg[0][lane] + simg[1][lane] + simg[2][lane] + simg[3][lane];
    }
}

// K5: out = holo * clean_key[w] (broadcast complex multiply)
// out_re = hr*a - hi*b ; out_im = hr*b + hi*a
__global__ __launch_bounds__(256) void k_out(
    const float* __restrict__ hr, const float* __restrict__ hi,
    const float* __restrict__ cre, const float* __restrict__ cim,
    float* __restrict__ out_re, float* __restrict__ out_im) {
    const int w = blockIdx.y;
    const size_t base = (size_t)w * SDIM;
    const int i = blockIdx.x * 256 + threadIdx.x;   // over SDIM/4 float4s
    const float a = cre[w], b = cim[w];
    const float4 h = ((const float4*)(hr + base))[i];
    const float4 g = ((const float4*)(hi + base))[i];
    float4 orr, oii;
    orr.x = h.x * a - g.x * b;  oii.x = h.x * b + g.x * a;
    orr.y = h.y * a - g.y * b;  oii.y = h.y * b + g.y * a;
    orr.z = h.z * a - g.z * b;  oii.z = h.z * b + g.z * a;
    orr.w = h.w * a - g.w * b;  oii.w = h.w * b + g.w * a;
    ((float4*)(out_re + base))[i] = orr;
    ((float4*)(out_im + base))[i] = oii;
}

extern "C" void kernel_launch(void* const* d_in, const int* in_sizes, int n_in,
                              void* d_out, int out_size, void* d_ws, size_t ws_size,
                              hipStream_t stream) {
    const float* hr = (const float*)d_in[0];
    const float* hi = (const float*)d_in[1];
    const float* cr = (const float*)d_in[2];
    const float* ci = (const float*)d_in[3];
    const float* kr = (const float*)d_in[4];
    const float* ki = (const float*)d_in[5];

    float* ws = (float*)d_ws;
    float* mix_re = ws;                 // 4096
    float* mix_im = ws + 4096;          // 4096
    float* corr   = ws + 8192;          // 1024
    float* att    = ws + 9216;          // 1024
    float* cre    = ws + 10240;         // 4096
    float* cim    = ws + 14336;         // 4096

    float* out_re = (float*)d_out;
    float* out_im = out_re + (size_t)WDIM * SDIM;

    k_mix<<<WDIM, 256, 0, stream>>>(hr, hi, cr, ci, mix_re, mix_im);
    k_corr<<<NKEYS, 256, 0, stream>>>(kr, ki, mix_re, mix_im, corr);
    k_softmax<<<1, 256, 0, stream>>>(corr, att);
    k_clean<<<WDIM / 64, 256, 0, stream>>>(kr, ki, att, cre, cim);
    k_out<<<dim3(SDIM / 1024, WDIM), 256, 0, stream>>>(hr, hi, cre, cim, out_re, out_im);
}

// Round 2
// 389.178 us; speedup vs baseline: 1.0032x; 1.0032x over previous
//
#include <hip/hip_runtime.h>
#include <math.h>

#define WDIM 4096
#define SDIM 4096
#define NKEYS 1024
#define SHARP 10.0f

__device__ __forceinline__ float wave_reduce_sum(float v) {
#pragma unroll
    for (int off = 32; off > 0; off >>= 1) v += __shfl_down(v, off, 64);
    return v;
}

// K1: noisy_mix[w] = sum_s holo[w,s] * conj(cue[w,s])
// One wave per row; 4 rows per block; 16 compile-time iterations/thread.
// re = hr*cr + hi*ci ; im = hi*cr - hr*ci
__global__ __launch_bounds__(256) void k_mix(
    const float* __restrict__ hr, const float* __restrict__ hi,
    const float* __restrict__ cr, const float* __restrict__ ci,
    float* __restrict__ mix_re, float* __restrict__ mix_im) {
    const int wave = threadIdx.x >> 6, lane = threadIdx.x & 63;
    const int w = blockIdx.x * 4 + wave;
    const size_t base = (size_t)w * SDIM;
    const float4* hr4 = (const float4*)(hr + base);
    const float4* hi4 = (const float4*)(hi + base);
    const float4* cr4 = (const float4*)(cr + base);
    const float4* ci4 = (const float4*)(ci + base);
    float sr = 0.f, si = 0.f;
#pragma unroll 4
    for (int i = 0; i < 16; ++i) {
        const int idx = lane + i * 64;
        float4 a = hr4[idx], b = hi4[idx], c = cr4[idx], d = ci4[idx];
        sr += a.x * c.x + b.x * d.x;  si += b.x * c.x - a.x * d.x;
        sr += a.y * c.y + b.y * d.y;  si += b.y * c.y - a.y * d.y;
        sr += a.z * c.z + b.z * d.z;  si += b.z * c.z - a.z * d.z;
        sr += a.w * c.w + b.w * d.w;  si += b.w * c.w - a.w * d.w;
    }
    sr = wave_reduce_sum(sr);
    si = wave_reduce_sum(si);
    if (lane == 0) { mix_re[w] = sr; mix_im[w] = si; }
}

// K2: corr[n] = |sum_w keys[n,w] * mix[w]| * SHARP (plain dot, NO conjugation)
// One wave per key; 4 keys per block.
// zr = kr*mr - ki*mi ; zi = kr*mi + ki*mr
__global__ __launch_bounds__(256) void k_corr(
    const float* __restrict__ kr, const float* __restrict__ ki,
    const float* __restrict__ mr, const float* __restrict__ mi,
    float* __restrict__ corr) {
    const int wave = threadIdx.x >> 6, lane = threadIdx.x & 63;
    const int n = blockIdx.x * 4 + wave;
    const size_t base = (size_t)n * WDIM;
    const float4* kr4 = (const float4*)(kr + base);
    const float4* ki4 = (const float4*)(ki + base);
    const float4* mr4 = (const float4*)mr;
    const float4* mi4 = (const float4*)mi;
    float zr = 0.f, zi = 0.f;
#pragma unroll 4
    for (int i = 0; i < 16; ++i) {
        const int idx = lane + i * 64;
        float4 a = kr4[idx], b = ki4[idx], m = mr4[idx], q = mi4[idx];
        zr += a.x * m.x - b.x * q.x;  zi += a.x * q.x + b.x * m.x;
        zr += a.y * m.y - b.y * q.y;  zi += a.y * q.y + b.y * m.y;
        zr += a.z * m.z - b.z * q.z;  zi += a.z * q.z + b.z * m.z;
        zr += a.w * m.w - b.w * q.w;  zi += a.w * q.w + b.w * m.w;
    }
    zr = wave_reduce_sum(zr);
    zi = wave_reduce_sum(zi);
    if (lane == 0) corr[n] = sqrtf(zr * zr + zi * zi) * SHARP;
}

// K3: att = softmax(corr) — single block, 256 threads, 4 logits/thread
__global__ __launch_bounds__(256) void k_softmax(
    const float* __restrict__ corr, float* __restrict__ att) {
    const int t = threadIdx.x;
    __shared__ float red[256];
    float v[4];
    float m = -1e30f;
#pragma unroll
    for (int j = 0; j < 4; ++j) { v[j] = corr[t + j * 256]; m = fmaxf(m, v[j]); }
    red[t] = m; __syncthreads();
    for (int s = 128; s > 0; s >>= 1) {
        if (t < s) red[t] = fmaxf(red[t], red[t + s]);
        __syncthreads();
    }
    const float mx = red[0];
    __syncthreads();
    float e[4]; float sum = 0.f;
#pragma unroll
    for (int j = 0; j < 4; ++j) { e[j] = expf(v[j] - mx); sum += e[j]; }
    red[t] = sum; __syncthreads();
    for (int s = 128; s > 0; s >>= 1) {
        if (t < s) red[t] += red[t + s];
        __syncthreads();
    }
    const float inv = 1.0f / red[0];
#pragma unroll
    for (int j = 0; j < 4; ++j) att[t + j * 256] = e[j] * inv;
}

// K4: clean_key[w] = sum_n att[n] * keys[n,w]
// grid (4 w-tiles, 64 n-chunks): block handles 1024 w (float4/thread) x 16 keys,
// accumulates locally then atomicAdd into zero-initialized cre/cim.
__global__ __launch_bounds__(256) void k_clean(
    const float* __restrict__ kr, const float* __restrict__ ki,
    const float* __restrict__ att,
    float* __restrict__ clean_re, float* __restrict__ clean_im) {
    const int wt = blockIdx.x;            // 0..3   (1024 w each)
    const int nc = blockIdx.y;            // 0..63  (16 keys each)
    const int f4 = wt * 256 + threadIdx.x;       // float4 column index 0..1023 within tile*... (global f4 = wt*256+t)
    const int n0 = nc * 16;
    float4 ar = make_float4(0.f, 0.f, 0.f, 0.f);
    float4 ai = make_float4(0.f, 0.f, 0.f, 0.f);
#pragma unroll 4
    for (int j = 0; j < 16; ++j) {
        const int n = n0 + j;
        const float a = att[n];
        const float4 x = ((const float4*)(kr + (size_t)n * WDIM))[f4];
        const float4 y = ((const float4*)(ki + (size_t)n * WDIM))[f4];
        ar.x += a * x.x; ar.y += a * x.y; ar.z += a * x.z; ar.w += a * x.w;
        ai.x += a * y.x; ai.y += a * y.y; ai.z += a * y.z; ai.w += a * y.w;
    }
    const int w = f4 * 4;
    atomicAdd(&clean_re[w + 0], ar.x); atomicAdd(&clean_re[w + 1], ar.y);
    atomicAdd(&clean_re[w + 2], ar.z); atomicAdd(&clean_re[w + 3], ar.w);
    atomicAdd(&clean_im[w + 0], ai.x); atomicAdd(&clean_im[w + 1], ai.y);
    atomicAdd(&clean_im[w + 2], ai.z); atomicAdd(&clean_im[w + 3], ai.w);
}

// K5: out = holo * clean_key[w] — one block per row, 4 float4s per thread.
// out_re = hr*a - hi*b ; out_im = hr*b + hi*a
__global__ __launch_bounds__(256) void k_out(
    const float* __restrict__ hr, const float* __restrict__ hi,
    const float* __restrict__ cre, const float* __restrict__ cim,
    float* __restrict__ out_re, float* __restrict__ out_im) {
    const int w = blockIdx.x;
    const size_t base = (size_t)w * SDIM;
    const float a = cre[w], b = cim[w];
    const float4* hr4 = (const float4*)(hr + base);
    const float4* hi4 = (const float4*)(hi + base);
    float4* or4 = (float4*)(out_re + base);
    float4* oi4 = (float4*)(out_im + base);
#pragma unroll
    for (int j = 0; j < 4; ++j) {
        const int i = threadIdx.x + j * 256;
        const float4 h = hr4[i];
        const float4 g = hi4[i];
        float4 orr, oii;
        orr.x = h.x * a - g.x * b;  oii.x = h.x * b + g.x * a;
        orr.y = h.y * a - g.y * b;  oii.y = h.y * b + g.y * a;
        orr.z = h.z * a - g.z * b;  oii.z = h.z * b + g.z * a;
        orr.w = h.w * a - g.w * b;  oii.w = h.w * b + g.w * a;
        or4[i] = orr;
        oi4[i] = oii;
    }
}

extern "C" void kernel_launch(void* const* d_in, const int* in_sizes, int n_in,
                              void* d_out, int out_size, void* d_ws, size_t ws_size,
                              hipStream_t stream) {
    const float* hr = (const float*)d_in[0];
    const float* hi = (const float*)d_in[1];
    const float* cr = (const float*)d_in[2];
    const float* ci = (const float*)d_in[3];
    const float* kr = (const float*)d_in[4];
    const float* ki = (const float*)d_in[5];

    float* ws = (float*)d_ws;
    float* mix_re = ws;                 // 4096
    float* mix_im = ws + 4096;          // 4096
    float* corr   = ws + 8192;          // 1024
    float* att    = ws + 9216;          // 1024
    float* cre    = ws + 10240;         // 4096
    float* cim    = ws + 14336;         // 4096 (contiguous with cre)

    float* out_re = (float*)d_out;
    float* out_im = out_re + (size_t)WDIM * SDIM;

    k_mix<<<WDIM / 4, 256, 0, stream>>>(hr, hi, cr, ci, mix_re, mix_im);
    k_corr<<<NKEYS / 4, 256, 0, stream>>>(kr, ki, mix_re, mix_im, corr);
    k_softmax<<<1, 256, 0, stream>>>(corr, att);
    hipMemsetAsync(cre, 0, 2 * WDIM * sizeof(float), stream);
    k_clean<<<dim3(4, 64), 256, 0, stream>>>(kr, ki, att, cre, cim);
    k_out<<<WDIM, 256, 0, stream>>>(hr, hi, cre, cim, out_re, out_im);
}

// Round 3
// 377.896 us; speedup vs baseline: 1.0332x; 1.0299x over previous
//
#include <hip/hip_runtime.h>
#include <math.h>

#define WDIM 4096
#define SDIM 4096
#define NKEYS 1024
#define SHARP 10.0f

typedef float v4 __attribute__((ext_vector_type(4)));

__device__ __forceinline__ float wave_reduce_sum(float v) {
#pragma unroll
    for (int off = 32; off > 0; off >>= 1) v += __shfl_down(v, off, 64);
    return v;
}

// K1: noisy_mix[w] = sum_s holo[w,s] * conj(cue[w,s])
// One wave per row, 4 rows/block. 16 float4 loads in flight per thread.
// cue is single-use -> nontemporal (don't evict holo from L3).
// re = hr*cr + hi*ci ; im = hi*cr - hr*ci
__global__ __launch_bounds__(256) void k_mix(
    const float* __restrict__ hr, const float* __restrict__ hi,
    const float* __restrict__ cr, const float* __restrict__ ci,
    float* __restrict__ mix_re, float* __restrict__ mix_im) {
    const int wave = threadIdx.x >> 6, lane = threadIdx.x & 63;
    const int w = blockIdx.x * 4 + wave;
    const size_t base = (size_t)w * SDIM;
    const v4* hr4 = (const v4*)(hr + base);
    const v4* hi4 = (const v4*)(hi + base);
    const v4* cr4 = (const v4*)(cr + base);
    const v4* ci4 = (const v4*)(ci + base);
    float sr = 0.f, si = 0.f;
#pragma unroll 1
    for (int it = 0; it < 4; ++it) {
        v4 a[4], b[4], c[4], d[4];
#pragma unroll
        for (int j = 0; j < 4; ++j) {
            const int idx = it * 256 + j * 64 + lane;
            a[j] = hr4[idx];
            b[j] = hi4[idx];
            c[j] = __builtin_nontemporal_load(cr4 + idx);
            d[j] = __builtin_nontemporal_load(ci4 + idx);
        }
#pragma unroll
        for (int j = 0; j < 4; ++j) {
            sr += a[j].x * c[j].x + b[j].x * d[j].x;  si += b[j].x * c[j].x - a[j].x * d[j].x;
            sr += a[j].y * c[j].y + b[j].y * d[j].y;  si += b[j].y * c[j].y - a[j].y * d[j].y;
            sr += a[j].z * c[j].z + b[j].z * d[j].z;  si += b[j].z * c[j].z - a[j].z * d[j].z;
            sr += a[j].w * c[j].w + b[j].w * d[j].w;  si += b[j].w * c[j].w - a[j].w * d[j].w;
        }
    }
    sr = wave_reduce_sum(sr);
    si = wave_reduce_sum(si);
    if (lane == 0) { mix_re[w] = sr; mix_im[w] = si; }
}

// K2: corr[n] = |sum_w keys[n,w] * mix[w]| * SHARP (plain dot, NO conjugation)
// One wave per key, 4 keys/block. zr = kr*mr - ki*mi ; zi = kr*mi + ki*mr
__global__ __launch_bounds__(256) void k_corr(
    const float* __restrict__ kr, const float* __restrict__ ki,
    const float* __restrict__ mr, const float* __restrict__ mi,
    float* __restrict__ corr) {
    const int wave = threadIdx.x >> 6, lane = threadIdx.x & 63;
    const int n = blockIdx.x * 4 + wave;
    const size_t base = (size_t)n * WDIM;
    const v4* kr4 = (const v4*)(kr + base);
    const v4* ki4 = (const v4*)(ki + base);
    const v4* mr4 = (const v4*)mr;
    const v4* mi4 = (const v4*)mi;
    float zr = 0.f, zi = 0.f;
#pragma unroll 1
    for (int it = 0; it < 4; ++it) {
        v4 a[4], b[4], m[4], q[4];
#pragma unroll
        for (int j = 0; j < 4; ++j) {
            const int idx = it * 256 + j * 64 + lane;
            a[j] = kr4[idx];
            b[j] = ki4[idx];
            m[j] = mr4[idx];
            q[j] = mi4[idx];
        }
#pragma unroll
        for (int j = 0; j < 4; ++j) {
            zr += a[j].x * m[j].x - b[j].x * q[j].x;  zi += a[j].x * q[j].x + b[j].x * m[j].x;
            zr += a[j].y * m[j].y - b[j].y * q[j].y;  zi += a[j].y * q[j].y + b[j].y * m[j].y;
            zr += a[j].z * m[j].z - b[j].z * q[j].z;  zi += a[j].z * q[j].z + b[j].z * m[j].z;
            zr += a[j].w * m[j].w - b[j].w * q[j].w;  zi += a[j].w * q[j].w + b[j].w * m[j].w;
        }
    }
    zr = wave_reduce_sum(zr);
    zi = wave_reduce_sum(zi);
    if (lane == 0) corr[n] = sqrtf(zr * zr + zi * zi) * SHARP;
}

// K3: att = softmax(corr) — single block, 256 threads, 4 logits/thread
__global__ __launch_bounds__(256) void k_softmax(
    const float* __restrict__ corr, float* __restrict__ att) {
    const int t = threadIdx.x;
    __shared__ float red[256];
    float v[4];
    float m = -1e30f;
#pragma unroll
    for (int j = 0; j < 4; ++j) { v[j] = corr[t + j * 256]; m = fmaxf(m, v[j]); }
    red[t] = m; __syncthreads();
    for (int s = 128; s > 0; s >>= 1) {
        if (t < s) red[t] = fmaxf(red[t], red[t + s]);
        __syncthreads();
    }
    const float mx = red[0];
    __syncthreads();
    float e[4]; float sum = 0.f;
#pragma unroll
    for (int j = 0; j < 4; ++j) { e[j] = expf(v[j] - mx); sum += e[j]; }
    red[t] = sum; __syncthreads();
    for (int s = 128; s > 0; s >>= 1) {
        if (t < s) red[t] += red[t + s];
        __syncthreads();
    }
    const float inv = 1.0f / red[0];
#pragma unroll
    for (int j = 0; j < 4; ++j) att[t + j * 256] = e[j] * inv;
}

// K4: clean_key[w] = sum_n att[n] * keys[n,w]
// grid (4 w-tiles, 64 n-chunks of 16 keys); batched 8-deep loads;
// partials atomicAdd'ed into zero-initialized cre/cim.
__global__ __launch_bounds__(256) void k_clean(
    const float* __restrict__ kr, const float* __restrict__ ki,
    const float* __restrict__ att,
    float* __restrict__ clean_re, float* __restrict__ clean_im) {
    const int wt = blockIdx.x;            // 0..3
    const int nc = blockIdx.y;            // 0..63
    const int f4 = wt * 256 + threadIdx.x;
    const int n0 = nc * 16;
    float arx = 0.f, ary = 0.f, arz = 0.f, arw = 0.f;
    float aix = 0.f, aiy = 0.f, aiz = 0.f, aiw = 0.f;
#pragma unroll 1
    for (int jt = 0; jt < 4; ++jt) {
        v4 x[4], y[4]; float a[4];
#pragma unroll
        for (int j = 0; j < 4; ++j) {
            const int n = n0 + jt * 4 + j;
            a[j] = att[n];
            x[j] = ((const v4*)(kr + (size_t)n * WDIM))[f4];
            y[j] = ((const v4*)(ki + (size_t)n * WDIM))[f4];
        }
#pragma unroll
        for (int j = 0; j < 4; ++j) {
            arx += a[j] * x[j].x; ary += a[j] * x[j].y; arz += a[j] * x[j].z; arw += a[j] * x[j].w;
            aix += a[j] * y[j].x; aiy += a[j] * y[j].y; aiz += a[j] * y[j].z; aiw += a[j] * y[j].w;
        }
    }
    const int w = f4 * 4;
    atomicAdd(&clean_re[w + 0], arx); atomicAdd(&clean_re[w + 1], ary);
    atomicAdd(&clean_re[w + 2], arz); atomicAdd(&clean_re[w + 3], arw);
    atomicAdd(&clean_im[w + 0], aix); atomicAdd(&clean_im[w + 1], aiy);
    atomicAdd(&clean_im[w + 2], aiz); atomicAdd(&clean_im[w + 3], aiw);
}

// K5: out = holo * clean_key[w] — one block/row, 8 loads in flight, NT stores
// (don't let 128 MiB of output evict holo/inputs from L3).
// out_re = hr*a - hi*b ; out_im = hr*b + hi*a
__global__ __launch_bounds__(256) void k_out(
    const float* __restrict__ hr, const float* __restrict__ hi,
    const float* __restrict__ cre, const float* __restrict__ cim,
    float* __restrict__ out_re, float* __restrict__ out_im) {
    const int w = blockIdx.x;
    const size_t base = (size_t)w * SDIM;
    const float a = cre[w], b = cim[w];
    const v4* hr4 = (const v4*)(hr + base);
    const v4* hi4 = (const v4*)(hi + base);
    v4* or4 = (v4*)(out_re + base);
    v4* oi4 = (v4*)(out_im + base);
    v4 h[4], g[4];
#pragma unroll
    for (int j = 0; j < 4; ++j) {
        const int i = threadIdx.x + j * 256;
        h[j] = hr4[i];
        g[j] = hi4[i];
    }
#pragma unroll
    for (int j = 0; j < 4; ++j) {
        const int i = threadIdx.x + j * 256;
        v4 orr, oii;
        orr.x = h[j].x * a - g[j].x * b;  oii.x = h[j].x * b + g[j].x * a;
        orr.y = h[j].y * a - g[j].y * b;  oii.y = h[j].y * b + g[j].y * a;
        orr.z = h[j].z * a - g[j].z * b;  oii.z = h[j].z * b + g[j].z * a;
        orr.w = h[j].w * a - g[j].w * b;  oii.w = h[j].w * b + g[j].w * a;
        __builtin_nontemporal_store(orr, or4 + i);
        __builtin_nontemporal_store(oii, oi4 + i);
    }
}

extern "C" void kernel_launch(void* const* d_in, const int* in_sizes, int n_in,
                              void* d_out, int out_size, void* d_ws, size_t ws_size,
                              hipStream_t stream) {
    const float* hr = (const float*)d_in[0];
    const float* hi = (const float*)d_in[1];
    const float* cr = (const float*)d_in[2];
    const float* ci = (const float*)d_in[3];
    const float* kr = (const float*)d_in[4];
    const float* ki = (const float*)d_in[5];

    float* ws = (float*)d_ws;
    float* mix_re = ws;                 // 4096
    float* mix_im = ws + 4096;          // 4096
    float* corr   = ws + 8192;          // 1024
    float* att    = ws + 9216;          // 1024
    float* cre    = ws + 10240;         // 4096
    float* cim    = ws + 14336;         // 4096 (contiguous with cre)

    float* out_re = (float*)d_out;
    float* out_im = out_re + (size_t)WDIM * SDIM;

    k_mix<<<WDIM / 4, 256, 0, stream>>>(hr, hi, cr, ci, mix_re, mix_im);
    k_corr<<<NKEYS / 4, 256, 0, stream>>>(kr, ki, mix_re, mix_im, corr);
    k_softmax<<<1, 256, 0, stream>>>(corr, att);
    hipMemsetAsync(cre, 0, 2 * WDIM * sizeof(float), stream);
    k_clean<<<dim3(4, 64), 256, 0, stream>>>(kr, ki, att, cre, cim);
    k_out<<<WDIM, 256, 0, stream>>>(hr, hi, cre, cim, out_re, out_im);
}